// Round 2
// baseline (408.943 us; speedup 1.0000x reference)
//
#include <hip/hip_runtime.h>
#include <hip/hip_cooperative_groups.h>

namespace cg = cooperative_groups;

#define NN 2048
#define HALF 1024
#define CC 128
#define EE 65536
#define CAP 128

typedef unsigned short u16;

__device__ __forceinline__ float sigm(float v){ return 1.0f/(1.0f + __expf(-v)); }

// Single cooperative kernel, 512 blocks x 256 threads (2 blocks/CU -> always co-resident).
// P0: sigmoid+colsum | edge bucketing | H0 = x@W1
// P1: layer1 aggregation -> partials (dense DP[4], sparse SP)  [no atomics]
// P2: mid: G' = (relu(SP+sum(DP)+b1) @ [Wmu|Wls]) * dinv[row]
// P3: layer2 aggregation on G' -> partials (DP/SP reused)      [no atomics]
// P4: out = bias + SP + sum(DP)
__global__ __launch_bounds__(256) void k_fused(
    const float* __restrict__ my, const int* __restrict__ ei, const float* __restrict__ x,
    const float* __restrict__ W1, const float* __restrict__ b1,
    const float* __restrict__ Wmu, const float* __restrict__ bmu,
    const float* __restrict__ Wls, const float* __restrict__ bls,
    float* __restrict__ SpRaw, float* __restrict__ colsum,
    int* __restrict__ cnt, u16* __restrict__ bucket,
    float* __restrict__ H0, float* __restrict__ Gm,
    float* __restrict__ SP, float* __restrict__ DP,
    float* __restrict__ out)
{
  __shared__ float sdinv[NN];     // persists across phases (block stays resident)
  __shared__ float la[8][CC];
  cg::grid_group grid = cg::this_grid();
  int b = blockIdx.x, t = threadIdx.x;

  // ================= P0 =================
  if (b < 128) {
    // SpRaw = sigmoid(my[:1024,:1024]), colsum atomics (only remaining atomics: 4K adds)
    int c0 = t*4;
    float cs0=0.f, cs1=0.f, cs2=0.f, cs3=0.f;
    #pragma unroll 2
    for (int rr=0; rr<8; ++rr){
      int r = b*8 + rr;
      float4 v = *(const float4*)(my + (size_t)r*NN + c0);
      float s0=sigm(v.x), s1=sigm(v.y), s2=sigm(v.z), s3=sigm(v.w);
      *(float4*)(SpRaw + (size_t)r*HALF + c0) = make_float4(s0,s1,s2,s3);
      cs0+=s0; cs1+=s1; cs2+=s2; cs3+=s3;
    }
    atomicAdd(&colsum[c0+0], cs0);
    atomicAdd(&colsum[c0+1], cs1);
    atomicAdd(&colsum[c0+2], cs2);
    atomicAdd(&colsum[c0+3], cs3);
  } else if (b < 256) {
    // bucket sparse edges by dst (512 edges/block)
    int e0 = (b-128)*512 + t;
    #pragma unroll
    for (int i=0;i<2;i++){
      int e = e0 + i*256;
      int s = ei[e], d = ei[EE + e];
      int slot = atomicAdd(&cnt[d], 1);
      if (slot < CAP) bucket[d*CAP + slot] = (u16)s;
    }
  } else {
    // H0 = x @ W1, 8 rows/block
    int row0 = (b-256)*8;
    #pragma unroll
    for (int i=0;i<4;i++){
      int idx = i*256 + t;
      la[idx>>7][idx&127] = x[(size_t)row0*CC + idx];
    }
    __syncthreads();
    int f = t & 127, rh = t >> 7;
    const float4* a0 = (const float4*)la[rh*4+0];
    const float4* a1 = (const float4*)la[rh*4+1];
    const float4* a2 = (const float4*)la[rh*4+2];
    const float4* a3 = (const float4*)la[rh*4+3];
    float o0=0.f, o1=0.f, o2=0.f, o3=0.f;
    #pragma unroll 4
    for (int k4=0;k4<32;k4++){
      float4 v0=a0[k4], v1=a1[k4], v2=a2[k4], v3=a3[k4];
      float w0 = W1[(k4*4+0)*CC + f];
      float w1 = W1[(k4*4+1)*CC + f];
      float w2 = W1[(k4*4+2)*CC + f];
      float w3 = W1[(k4*4+3)*CC + f];
      o0=fmaf(v0.x,w0,o0); o0=fmaf(v0.y,w1,o0); o0=fmaf(v0.z,w2,o0); o0=fmaf(v0.w,w3,o0);
      o1=fmaf(v1.x,w0,o1); o1=fmaf(v1.y,w1,o1); o1=fmaf(v1.z,w2,o1); o1=fmaf(v1.w,w3,o1);
      o2=fmaf(v2.x,w0,o2); o2=fmaf(v2.y,w1,o2); o2=fmaf(v2.z,w2,o2); o2=fmaf(v2.w,w3,o2);
      o3=fmaf(v3.x,w0,o3); o3=fmaf(v3.y,w1,o3); o3=fmaf(v3.z,w2,o3); o3=fmaf(v3.w,w3,o3);
    }
    H0[(size_t)(row0 + rh*4 + 0)*CC + f] = o0;
    H0[(size_t)(row0 + rh*4 + 1)*CC + f] = o1;
    H0[(size_t)(row0 + rh*4 + 2)*CC + f] = o2;
    H0[(size_t)(row0 + rh*4 + 3)*CC + f] = o3;
  }
  grid.sync();

  // ---- dinv table (built once, reused P1..P4)
  #pragma unroll
  for (int i=0;i<8;i++){
    int j = i*256 + t;
    float cs = (j < HALF) ? colsum[j] : 0.0f;
    sdinv[j] = rsqrtf(1.0f + (float)cnt[j] + cs);
  }
  __syncthreads();

  // ================= P1: AGG1 partials =================
  if (b < 256) {
    // dense: 16 d/block, 4 r-chunks -> DP[chunk][d][f], plain stores
    int lane = t & 63, f0 = lane*2;
    int dbase = (b>>2)*16 + (t>>6)*4;
    int chunk = b & 3;
    int r0 = chunk*256;
    float a00=0.f,a01=0.f,a10=0.f,a11=0.f,a20=0.f,a21=0.f,a30=0.f,a31=0.f;
    #pragma unroll 4
    for (int rr=0; rr<256; ++rr){
      int r = r0 + rr;
      float2 fv = *(const float2*)(H0 + (size_t)r*CC + f0);
      float sc = sdinv[r];
      float fx = fv.x*sc, fy = fv.y*sc;
      float4 s4 = *(const float4*)(SpRaw + (size_t)r*HALF + dbase);
      a00=fmaf(s4.x,fx,a00); a01=fmaf(s4.x,fy,a01);
      a10=fmaf(s4.y,fx,a10); a11=fmaf(s4.y,fy,a11);
      a20=fmaf(s4.z,fx,a20); a21=fmaf(s4.z,fy,a21);
      a30=fmaf(s4.w,fx,a30); a31=fmaf(s4.w,fy,a31);
    }
    float d0=sdinv[dbase+0], d1=sdinv[dbase+1], d2=sdinv[dbase+2], d3=sdinv[dbase+3];
    float* o = DP + ((size_t)chunk*HALF + dbase)*CC + f0;
    o[0*CC+0]=a00*d0; o[0*CC+1]=a01*d0;
    o[1*CC+0]=a10*d1; o[1*CC+1]=a11*d1;
    o[2*CC+0]=a20*d2; o[2*CC+1]=a21*d2;
    o[3*CC+0]=a30*d3; o[3*CC+1]=a31*d3;
  } else {
    // sparse: 8 dst/block, half-wave per dst, float4 features
    int w = t>>6, hw = (t>>5)&1, l = t&31;
    int d = (b-256)*8 + w*2 + hw;
    int f0 = l*4;
    float dd = sdinv[d];
    float4 sv = *(const float4*)(H0 + (size_t)d*CC + f0);
    float ax=dd*sv.x, ay=dd*sv.y, az=dd*sv.z, aw=dd*sv.w;   // self-loop
    int m = cnt[d]; m = m > CAP ? CAP : m;
    const u16* bk = bucket + d*CAP;
    int j = 0;
    for (; j+1 < m; j += 2){
      unsigned pr = *(const unsigned*)(bk + j);
      int s0 = pr & 0xffff, s1 = pr >> 16;
      float w0 = sdinv[s0], w1 = sdinv[s1];
      float4 v0 = *(const float4*)(H0 + (size_t)s0*CC + f0);
      float4 v1 = *(const float4*)(H0 + (size_t)s1*CC + f0);
      ax=fmaf(w0,v0.x,ax); ay=fmaf(w0,v0.y,ay); az=fmaf(w0,v0.z,az); aw=fmaf(w0,v0.w,aw);
      ax=fmaf(w1,v1.x,ax); ay=fmaf(w1,v1.y,ay); az=fmaf(w1,v1.z,az); aw=fmaf(w1,v1.w,aw);
    }
    if (j < m){
      int s0 = bk[j];
      float w0 = sdinv[s0];
      float4 v0 = *(const float4*)(H0 + (size_t)s0*CC + f0);
      ax=fmaf(w0,v0.x,ax); ay=fmaf(w0,v0.y,ay); az=fmaf(w0,v0.z,az); aw=fmaf(w0,v0.w,aw);
    }
    *(float4*)(SP + (size_t)d*CC + f0) = make_float4(dd*ax, dd*ay, dd*az, dd*aw);
  }
  grid.sync();

  // ================= P2: mid (4 rows/block) =================
  {
    int row0 = b*4;
    #pragma unroll
    for (int i=0;i<2;i++){
      int idx = i*256 + t;
      int r = row0 + (idx>>7), c = idx & 127;
      float v = SP[(size_t)r*CC + c];
      if (row0 < HALF)
        v += DP[((size_t)0*HALF + r)*CC + c] + DP[((size_t)1*HALF + r)*CC + c]
           + DP[((size_t)2*HALF + r)*CC + c] + DP[((size_t)3*HALF + r)*CC + c];
      v += b1[c];
      la[idx>>7][c] = v > 0.f ? v : 0.f;
    }
    __syncthreads();
    int f = t & 127, rh = t >> 7, g = f & 63;
    const float* W = (f < 64) ? Wmu : Wls;
    const float4* a0 = (const float4*)la[rh*2+0];
    const float4* a1 = (const float4*)la[rh*2+1];
    float o0=0.f, o1=0.f;
    #pragma unroll 4
    for (int k4=0;k4<32;k4++){
      float4 v0=a0[k4], v1=a1[k4];
      float w0 = W[(k4*4+0)*64 + g];
      float w1 = W[(k4*4+1)*64 + g];
      float w2 = W[(k4*4+2)*64 + g];
      float w3 = W[(k4*4+3)*64 + g];
      o0=fmaf(v0.x,w0,o0); o0=fmaf(v0.y,w1,o0); o0=fmaf(v0.z,w2,o0); o0=fmaf(v0.w,w3,o0);
      o1=fmaf(v1.x,w0,o1); o1=fmaf(v1.y,w1,o1); o1=fmaf(v1.z,w2,o1); o1=fmaf(v1.w,w3,o1);
    }
    int rA = row0 + rh*2;
    Gm[(size_t)(rA+0)*CC + f] = o0 * sdinv[rA+0];
    Gm[(size_t)(rA+1)*CC + f] = o1 * sdinv[rA+1];
  }
  grid.sync();

  // ================= P3: layer2 partials (DP/SP reused) =================
  if (b < 256) {
    int lane = t & 63, f0 = lane*2;
    int dbase = (b>>2)*16 + (t>>6)*4;
    int chunk = b & 3;
    int r0 = chunk*256;
    float a00=0.f,a01=0.f,a10=0.f,a11=0.f,a20=0.f,a21=0.f,a30=0.f,a31=0.f;
    #pragma unroll 4
    for (int rr=0; rr<256; ++rr){
      int r = r0 + rr;
      float2 gv = *(const float2*)(Gm + (size_t)r*CC + f0);   // pre-scaled by dinv[r]
      float4 s4 = *(const float4*)(SpRaw + (size_t)r*HALF + dbase);
      a00=fmaf(s4.x,gv.x,a00); a01=fmaf(s4.x,gv.y,a01);
      a10=fmaf(s4.y,gv.x,a10); a11=fmaf(s4.y,gv.y,a11);
      a20=fmaf(s4.z,gv.x,a20); a21=fmaf(s4.z,gv.y,a21);
      a30=fmaf(s4.w,gv.x,a30); a31=fmaf(s4.w,gv.y,a31);
    }
    float d0=sdinv[dbase+0], d1=sdinv[dbase+1], d2=sdinv[dbase+2], d3=sdinv[dbase+3];
    float* o = DP + ((size_t)chunk*HALF + dbase)*CC + f0;
    o[0*CC+0]=a00*d0; o[0*CC+1]=a01*d0;
    o[1*CC+0]=a10*d1; o[1*CC+1]=a11*d1;
    o[2*CC+0]=a20*d2; o[2*CC+1]=a21*d2;
    o[3*CC+0]=a30*d3; o[3*CC+1]=a31*d3;
  } else {
    int w = t>>6, hw = (t>>5)&1, l = t&31;
    int d = (b-256)*8 + w*2 + hw;
    int f0 = l*4;
    float dd = sdinv[d];
    float4 a = *(const float4*)(Gm + (size_t)d*CC + f0);      // self (pre-scaled)
    float ax=a.x, ay=a.y, az=a.z, aw=a.w;
    int m = cnt[d]; m = m > CAP ? CAP : m;
    const u16* bk = bucket + d*CAP;
    int j = 0;
    for (; j+1 < m; j += 2){
      unsigned pr = *(const unsigned*)(bk + j);
      int s0 = pr & 0xffff, s1 = pr >> 16;
      float4 v0 = *(const float4*)(Gm + (size_t)s0*CC + f0);
      float4 v1 = *(const float4*)(Gm + (size_t)s1*CC + f0);
      ax += v0.x + v1.x; ay += v0.y + v1.y;
      az += v0.z + v1.z; aw += v0.w + v1.w;
    }
    if (j < m){
      int s0 = bk[j];
      float4 v0 = *(const float4*)(Gm + (size_t)s0*CC + f0);
      ax += v0.x; ay += v0.y; az += v0.z; aw += v0.w;
    }
    *(float4*)(SP + (size_t)d*CC + f0) = make_float4(dd*ax, dd*ay, dd*az, dd*aw);
  }
  grid.sync();

  // ================= P4: combine -> out (bias + SP + sum DP), float2/thread
  {
    int tid = b*256 + t;               // [0, 131072)
    int half = tid >> 16;              // 65536 float2 per half
    int rem = tid & 65535;
    int d = rem >> 5;                  // 32 float2 per row of 64
    int g0 = (rem & 31)*2;
    int f = g0 + (half << 6);
    const float* bb = half ? bls : bmu;
    float vx = bb[g0], vy = bb[g0+1];
    const float* sp = SP + (size_t)d*CC + f;
    vx += sp[0]; vy += sp[1];
    if (d < HALF){
      #pragma unroll
      for (int k=0;k<4;k++){
        const float* dp = DP + ((size_t)k*HALF + d)*CC + f;
        vx += dp[0]; vy += dp[1];
      }
    }
    *(float2*)(out + ((size_t)half*NN + d)*64 + g0) = make_float2(vx, vy);
  }
}

extern "C" void kernel_launch(void* const* d_in, const int* in_sizes, int n_in,
                              void* d_out, int out_size, void* d_ws, size_t ws_size,
                              hipStream_t stream)
{
  (void)in_sizes; (void)n_in; (void)out_size; (void)ws_size;
  const float* x   = (const float*)d_in[0];
  const float* my  = (const float*)d_in[1];
  const float* W1  = (const float*)d_in[2];
  const float* b1  = (const float*)d_in[3];
  const float* Wmu = (const float*)d_in[4];
  const float* bmu = (const float*)d_in[5];
  const float* Wls = (const float*)d_in[6];
  const float* bls = (const float*)d_in[7];
  const int*   ei  = (const int*)d_in[8];
  float* out = (float*)d_out;
  char* ws = (char*)d_ws;

  // ws layout — memset covers only [0, 12288): cnt, colsum
  int*   cnt    = (int*)  (ws + 0);        //    8192 B (memset 0)
  float* colsum = (float*)(ws + 8192);     //    4096 B (memset 0)
  u16*   bucket = (u16*)  (ws + 12288);    //  524288 B
  float* SpRaw  = (float*)(ws + 536576);   // 4194304 B
  float* H0     = (float*)(ws + 4730880);  // 1048576 B
  float* Gm     = (float*)(ws + 5779456);  // 1048576 B
  float* SP     = (float*)(ws + 6828032);  // 1048576 B  (2048*128*4)
  float* DP     = (float*)(ws + 7876608);  // 2097152 B  (4*1024*128*4)

  hipMemsetAsync(ws, 0, 12288, stream);

  void* args[] = {
    (void*)&my, (void*)&ei, (void*)&x, (void*)&W1, (void*)&b1,
    (void*)&Wmu, (void*)&bmu, (void*)&Wls, (void*)&bls,
    (void*)&SpRaw, (void*)&colsum, (void*)&cnt, (void*)&bucket,
    (void*)&H0, (void*)&Gm, (void*)&SP, (void*)&DP, (void*)&out
  };
  hipLaunchCooperativeKernel(reinterpret_cast<const void*>(k_fused),
                             dim3(512), dim3(256), args, 0, stream);
}

// Round 3
// 257.815 us; speedup vs baseline: 1.5862x; 1.5862x over previous
//
#include <hip/hip_runtime.h>

#define NN 2048
#define HALF 1024
#define CC 128
#define EE 65536
#define CAP 128
#define NB 512

typedef unsigned short u16;

__device__ __forceinline__ float sigm(float v){ return 1.0f/(1.0f + __expf(-v)); }

// Lightweight grid barrier: all NB blocks must be co-resident
// (guaranteed: 512 blocks, launch_bounds(256,2) -> 2 blocks/CU on 256 CUs).
__device__ __forceinline__ void gbar(int* bar, int nb){
  __syncthreads();
  if (threadIdx.x == 0){
    __threadfence();                                   // release: publish our writes
    __hip_atomic_fetch_add(bar, 1, __ATOMIC_RELEASE, __HIP_MEMORY_SCOPE_AGENT);
    while (__hip_atomic_load(bar, __ATOMIC_RELAXED, __HIP_MEMORY_SCOPE_AGENT) < nb)
      __builtin_amdgcn_s_sleep(16);                    // ~1024 cyc between polls
    __threadfence();                                   // acquire: invalidate stale lines
  }
  __syncthreads();
}

// ---------------- KA: prep (512 blocks)
//  all: bias-seed out
//  [0,128):   SpRaw = sigmoid(my), colsum atomics
//  [128,256): bucket sparse edges by dst (512 edges/block)
//  [256,512): H0 = x @ W1 (8 rows/block)
__global__ __launch_bounds__(256) void k_prep(
    const float* __restrict__ my, const int* __restrict__ ei, const float* __restrict__ x,
    const float* __restrict__ W1,
    const float* __restrict__ bmu, const float* __restrict__ bls,
    float* __restrict__ SpRaw, float* __restrict__ colsum,
    int* __restrict__ cnt, u16* __restrict__ bucket, float* __restrict__ H0,
    float* __restrict__ out)
{
  __shared__ float la[8][CC];
  int b = blockIdx.x, t = threadIdx.x;
  int gid = b*256 + t;                    // 0..131071
  if (gid < 65536) {                      // 65536 float4 = full out
    int g4 = (gid & 15)*4;
    const float* bb = (gid < 32768) ? bmu : bls;
    ((float4*)out)[gid] = make_float4(bb[g4], bb[g4+1], bb[g4+2], bb[g4+3]);
  }

  if (b < 128) {
    int c0 = t*4;
    float cs0=0.f, cs1=0.f, cs2=0.f, cs3=0.f;
    #pragma unroll 2
    for (int rr=0; rr<8; ++rr){
      int r = b*8 + rr;
      float4 v = *(const float4*)(my + (size_t)r*NN + c0);
      float s0=sigm(v.x), s1=sigm(v.y), s2=sigm(v.z), s3=sigm(v.w);
      *(float4*)(SpRaw + (size_t)r*HALF + c0) = make_float4(s0,s1,s2,s3);
      cs0+=s0; cs1+=s1; cs2+=s2; cs3+=s3;
    }
    atomicAdd(&colsum[c0+0], cs0);
    atomicAdd(&colsum[c0+1], cs1);
    atomicAdd(&colsum[c0+2], cs2);
    atomicAdd(&colsum[c0+3], cs3);
  } else if (b < 256) {
    int e0 = (b-128)*512 + t;
    #pragma unroll
    for (int i=0;i<2;i++){
      int e = e0 + i*256;
      int s = ei[e], d = ei[EE + e];
      int slot = atomicAdd(&cnt[d], 1);
      if (slot < CAP) bucket[d*CAP + slot] = (u16)s;
    }
  } else {
    int row0 = (b-256)*8;
    #pragma unroll
    for (int i=0;i<4;i++){
      int idx = i*256 + t;
      la[idx>>7][idx&127] = x[(size_t)row0*CC + idx];
    }
    __syncthreads();
    int f = t & 127, rh = t >> 7;
    const float4* a0 = (const float4*)la[rh*4+0];
    const float4* a1 = (const float4*)la[rh*4+1];
    const float4* a2 = (const float4*)la[rh*4+2];
    const float4* a3 = (const float4*)la[rh*4+3];
    float o0=0.f, o1=0.f, o2=0.f, o3=0.f;
    #pragma unroll 4
    for (int k4=0;k4<32;k4++){
      float4 v0=a0[k4], v1=a1[k4], v2=a2[k4], v3=a3[k4];
      float w0 = W1[(k4*4+0)*CC + f];
      float w1 = W1[(k4*4+1)*CC + f];
      float w2 = W1[(k4*4+2)*CC + f];
      float w3 = W1[(k4*4+3)*CC + f];
      o0=fmaf(v0.x,w0,o0); o0=fmaf(v0.y,w1,o0); o0=fmaf(v0.z,w2,o0); o0=fmaf(v0.w,w3,o0);
      o1=fmaf(v1.x,w0,o1); o1=fmaf(v1.y,w1,o1); o1=fmaf(v1.z,w2,o1); o1=fmaf(v1.w,w3,o1);
      o2=fmaf(v2.x,w0,o2); o2=fmaf(v2.y,w1,o2); o2=fmaf(v2.z,w2,o2); o2=fmaf(v2.w,w3,o2);
      o3=fmaf(v3.x,w0,o3); o3=fmaf(v3.y,w1,o3); o3=fmaf(v3.z,w2,o3); o3=fmaf(v3.w,w3,o3);
    }
    H0[(size_t)(row0 + rh*4 + 0)*CC + f] = o0;
    H0[(size_t)(row0 + rh*4 + 1)*CC + f] = o1;
    H0[(size_t)(row0 + rh*4 + 2)*CC + f] = o2;
    H0[(size_t)(row0 + rh*4 + 3)*CC + f] = o3;
  }
}

// ---------------- KB: main (512 blocks, 2 internal barriers)
//  P1: layer1 partials -> DP (dense chunks) / SP (sparse), no atomics
//  P2: Gm = (relu(SP+sumDP+b1) @ [Wmu|Wls]) * dinv[row]
//  P3: layer2 aggregation, atomics into bias-seeded out
__global__ __launch_bounds__(256,2) void k_main(
  const float* __restrict__ SpRaw, const float* __restrict__ H0,
  const float* __restrict__ b1,
  const float* __restrict__ Wmu, const float* __restrict__ Wls,
  const int* __restrict__ cnt, const float* __restrict__ colsum,
  const u16* __restrict__ bucket,
  float* __restrict__ Gm, float* __restrict__ SP, float* __restrict__ DP,
  int* __restrict__ bar, float* __restrict__ out)
{
  __shared__ float sdinv[NN];
  __shared__ float la[8][CC];
  int b = blockIdx.x, t = threadIdx.x;

  // dinv table (cnt/colsum visible via kernel boundary), persists all phases
  #pragma unroll
  for (int i=0;i<8;i++){
    int j = i*256 + t;
    float cs = (j < HALF) ? colsum[j] : 0.0f;
    sdinv[j] = rsqrtf(1.0f + (float)cnt[j] + cs);
  }
  __syncthreads();

  // ================= P1 =================
  if (b < 256) {
    int lane = t & 63, f0 = lane*2;
    int dbase = (b>>2)*16 + (t>>6)*4;
    int chunk = b & 3;
    int r0 = chunk*256;
    float a00=0.f,a01=0.f,a10=0.f,a11=0.f,a20=0.f,a21=0.f,a30=0.f,a31=0.f;
    #pragma unroll 4
    for (int rr=0; rr<256; ++rr){
      int r = r0 + rr;
      float2 fv = *(const float2*)(H0 + (size_t)r*CC + f0);
      float sc = sdinv[r];
      float fx = fv.x*sc, fy = fv.y*sc;
      float4 s4 = *(const float4*)(SpRaw + (size_t)r*HALF + dbase);
      a00=fmaf(s4.x,fx,a00); a01=fmaf(s4.x,fy,a01);
      a10=fmaf(s4.y,fx,a10); a11=fmaf(s4.y,fy,a11);
      a20=fmaf(s4.z,fx,a20); a21=fmaf(s4.z,fy,a21);
      a30=fmaf(s4.w,fx,a30); a31=fmaf(s4.w,fy,a31);
    }
    float d0=sdinv[dbase+0], d1=sdinv[dbase+1], d2=sdinv[dbase+2], d3=sdinv[dbase+3];
    float* o = DP + ((size_t)chunk*HALF + dbase)*CC + f0;
    o[0*CC+0]=a00*d0; o[0*CC+1]=a01*d0;
    o[1*CC+0]=a10*d1; o[1*CC+1]=a11*d1;
    o[2*CC+0]=a20*d2; o[2*CC+1]=a21*d2;
    o[3*CC+0]=a30*d3; o[3*CC+1]=a31*d3;
  } else {
    int w = t>>6, hw = (t>>5)&1, l = t&31;
    int d = (b-256)*8 + w*2 + hw;
    int f0 = l*4;
    float dd = sdinv[d];
    float4 sv = *(const float4*)(H0 + (size_t)d*CC + f0);
    float ax=dd*sv.x, ay=dd*sv.y, az=dd*sv.z, aw=dd*sv.w;   // self-loop
    int m = cnt[d]; m = m > CAP ? CAP : m;
    const u16* bk = bucket + d*CAP;
    int j = 0;
    for (; j+1 < m; j += 2){
      unsigned pr = *(const unsigned*)(bk + j);
      int s0 = pr & 0xffff, s1 = pr >> 16;
      float w0 = sdinv[s0], w1 = sdinv[s1];
      float4 v0 = *(const float4*)(H0 + (size_t)s0*CC + f0);
      float4 v1 = *(const float4*)(H0 + (size_t)s1*CC + f0);
      ax=fmaf(w0,v0.x,ax); ay=fmaf(w0,v0.y,ay); az=fmaf(w0,v0.z,az); aw=fmaf(w0,v0.w,aw);
      ax=fmaf(w1,v1.x,ax); ay=fmaf(w1,v1.y,ay); az=fmaf(w1,v1.z,az); aw=fmaf(w1,v1.w,aw);
    }
    if (j < m){
      int s0 = bk[j];
      float w0 = sdinv[s0];
      float4 v0 = *(const float4*)(H0 + (size_t)s0*CC + f0);
      ax=fmaf(w0,v0.x,ax); ay=fmaf(w0,v0.y,ay); az=fmaf(w0,v0.z,az); aw=fmaf(w0,v0.w,aw);
    }
    *(float4*)(SP + (size_t)d*CC + f0) = make_float4(dd*ax, dd*ay, dd*az, dd*aw);
  }
  gbar(&bar[0], NB);

  // ================= P2 =================
  {
    int row0 = b*4;
    #pragma unroll
    for (int i=0;i<2;i++){
      int idx = i*256 + t;
      int r = row0 + (idx>>7), c = idx & 127;
      float v = SP[(size_t)r*CC + c];
      if (row0 < HALF)
        v += DP[((size_t)0*HALF + r)*CC + c] + DP[((size_t)1*HALF + r)*CC + c]
           + DP[((size_t)2*HALF + r)*CC + c] + DP[((size_t)3*HALF + r)*CC + c];
      v += b1[c];
      la[idx>>7][c] = v > 0.f ? v : 0.f;
    }
    __syncthreads();
    int f = t & 127, rh = t >> 7, g = f & 63;
    const float* W = (f < 64) ? Wmu : Wls;
    const float4* a0 = (const float4*)la[rh*2+0];
    const float4* a1 = (const float4*)la[rh*2+1];
    float o0=0.f, o1=0.f;
    #pragma unroll 4
    for (int k4=0;k4<32;k4++){
      float4 v0=a0[k4], v1=a1[k4];
      float w0 = W[(k4*4+0)*64 + g];
      float w1 = W[(k4*4+1)*64 + g];
      float w2 = W[(k4*4+2)*64 + g];
      float w3 = W[(k4*4+3)*64 + g];
      o0=fmaf(v0.x,w0,o0); o0=fmaf(v0.y,w1,o0); o0=fmaf(v0.z,w2,o0); o0=fmaf(v0.w,w3,o0);
      o1=fmaf(v1.x,w0,o1); o1=fmaf(v1.y,w1,o1); o1=fmaf(v1.z,w2,o1); o1=fmaf(v1.w,w3,o1);
    }
    int rA = row0 + rh*2;
    Gm[(size_t)(rA+0)*CC + f] = o0 * sdinv[rA+0];
    Gm[(size_t)(rA+1)*CC + f] = o1 * sdinv[rA+1];
  }
  gbar(&bar[1], NB);

  // ================= P3: layer2 -> atomics into bias-seeded out =================
  if (b < 256) {
    int lane = t & 63, f0 = lane*2;
    size_t obase = (f0 < 64) ? 0 : (size_t)NN*64;
    int g0 = f0 & 63;
    int dbase = (b>>2)*16 + (t>>6)*4;
    int r0 = (b&3)*256;
    float a00=0.f,a01=0.f,a10=0.f,a11=0.f,a20=0.f,a21=0.f,a30=0.f,a31=0.f;
    #pragma unroll 4
    for (int rr=0; rr<256; ++rr){
      int r = r0 + rr;
      float2 gv = *(const float2*)(Gm + (size_t)r*CC + f0);   // pre-scaled by dinv[r]
      float4 s4 = *(const float4*)(SpRaw + (size_t)r*HALF + dbase);
      a00=fmaf(s4.x,gv.x,a00); a01=fmaf(s4.x,gv.y,a01);
      a10=fmaf(s4.y,gv.x,a10); a11=fmaf(s4.y,gv.y,a11);
      a20=fmaf(s4.z,gv.x,a20); a21=fmaf(s4.z,gv.y,a21);
      a30=fmaf(s4.w,gv.x,a30); a31=fmaf(s4.w,gv.y,a31);
    }
    float d0=sdinv[dbase+0], d1=sdinv[dbase+1], d2=sdinv[dbase+2], d3=sdinv[dbase+3];
    float* o = out + obase + (size_t)dbase*64 + g0;
    atomicAdd(o + 0*64 + 0, a00*d0); atomicAdd(o + 0*64 + 1, a01*d0);
    atomicAdd(o + 1*64 + 0, a10*d1); atomicAdd(o + 1*64 + 1, a11*d1);
    atomicAdd(o + 2*64 + 0, a20*d2); atomicAdd(o + 2*64 + 1, a21*d2);
    atomicAdd(o + 3*64 + 0, a30*d3); atomicAdd(o + 3*64 + 1, a31*d3);
  } else {
    int w = t>>6, hw = (t>>5)&1, l = t&31;
    int d = (b-256)*8 + w*2 + hw;
    int f0 = l*4;
    size_t obase = (f0 < 64) ? 0 : (size_t)NN*64;
    int g0 = f0 & 63;
    float4 a = *(const float4*)(Gm + (size_t)d*CC + f0);      // self (pre-scaled)
    float ax=a.x, ay=a.y, az=a.z, aw=a.w;
    int m = cnt[d]; m = m > CAP ? CAP : m;
    const u16* bk = bucket + d*CAP;
    int j = 0;
    for (; j+1 < m; j += 2){
      unsigned pr = *(const unsigned*)(bk + j);
      int s0 = pr & 0xffff, s1 = pr >> 16;
      float4 v0 = *(const float4*)(Gm + (size_t)s0*CC + f0);
      float4 v1 = *(const float4*)(Gm + (size_t)s1*CC + f0);
      ax += v0.x + v1.x; ay += v0.y + v1.y;
      az += v0.z + v1.z; aw += v0.w + v1.w;
    }
    if (j < m){
      int s0 = bk[j];
      float4 v0 = *(const float4*)(Gm + (size_t)s0*CC + f0);
      ax += v0.x; ay += v0.y; az += v0.z; aw += v0.w;
    }
    float dd = sdinv[d];
    float* o = out + obase + (size_t)d*64 + g0;
    atomicAdd(o + 0, dd*ax); atomicAdd(o + 1, dd*ay);
    atomicAdd(o + 2, dd*az); atomicAdd(o + 3, dd*aw);
  }
}

extern "C" void kernel_launch(void* const* d_in, const int* in_sizes, int n_in,
                              void* d_out, int out_size, void* d_ws, size_t ws_size,
                              hipStream_t stream)
{
  (void)in_sizes; (void)n_in; (void)out_size; (void)ws_size;
  const float* x   = (const float*)d_in[0];
  const float* my  = (const float*)d_in[1];
  const float* W1  = (const float*)d_in[2];
  const float* b1  = (const float*)d_in[3];
  const float* Wmu = (const float*)d_in[4];
  const float* bmu = (const float*)d_in[5];
  const float* Wls = (const float*)d_in[6];
  const float* bls = (const float*)d_in[7];
  const int*   ei  = (const int*)d_in[8];
  float* out = (float*)d_out;
  char* ws = (char*)d_ws;

  // ws layout — memset covers [0, 12544): cnt, colsum, bar
  int*   cnt    = (int*)  (ws + 0);        //    8192 B (memset 0)
  float* colsum = (float*)(ws + 8192);     //    4096 B (memset 0)
  int*   bar    = (int*)  (ws + 12288);    //     256 B (memset 0)
  u16*   bucket = (u16*)  (ws + 12544);    //  524288 B
  float* SpRaw  = (float*)(ws + 536832);   // 4194304 B
  float* H0     = (float*)(ws + 4731136);  // 1048576 B
  float* Gm     = (float*)(ws + 5779712);  // 1048576 B
  float* SP     = (float*)(ws + 6828288);  // 1048576 B
  float* DP     = (float*)(ws + 7876864);  // 2097152 B

  hipMemsetAsync(ws, 0, 12544, stream);
  k_prep<<<512, 256, 0, stream>>>(my, ei, x, W1, bmu, bls,
                                  SpRaw, colsum, cnt, bucket, H0, out);
  k_main<<<512, 256, 0, stream>>>(SpRaw, H0, b1, Wmu, Wls, cnt, colsum,
                                  bucket, Gm, SP, DP, bar, out);
}

// Round 4
// 153.905 us; speedup vs baseline: 2.6571x; 1.6752x over previous
//
#include <hip/hip_runtime.h>

#define NN 2048
#define HALF 1024
#define CC 128
#define EE 65536
#define CAP 128

typedef unsigned short u16;

__device__ __forceinline__ float sigm(float v){ return 1.0f/(1.0f + __expf(-v)); }

__device__ __forceinline__ float dinv_lo(int i, const int* __restrict__ cnt,
                                         const float* __restrict__ colsum){
  return rsqrtf(1.0f + (float)cnt[i] + colsum[i]);
}
__device__ __forceinline__ float dinv_any(int i, const int* __restrict__ cnt,
                                          const float* __restrict__ colsum){
  float cs = (i < HALF) ? colsum[i] : 0.0f;
  return rsqrtf(1.0f + (float)cnt[i] + cs);
}

// ---------------- K1: prep (512 blocks)
//  all: bias-seed out
//  [0,128):   SpRaw = sigmoid(my), colsum atomics
//  [128,256): bucket sparse edges by dst (512 edges/block)
//  [256,512): H0 = x @ W1 (8 rows/block)
__global__ __launch_bounds__(256) void k_prep(
    const float* __restrict__ my, const int* __restrict__ ei, const float* __restrict__ x,
    const float* __restrict__ W1,
    const float* __restrict__ bmu, const float* __restrict__ bls,
    float* __restrict__ SpRaw, float* __restrict__ colsum,
    int* __restrict__ cnt, u16* __restrict__ bucket, float* __restrict__ H0,
    float* __restrict__ out)
{
  __shared__ float la[8][CC];
  int b = blockIdx.x, t = threadIdx.x;
  int gid = b*256 + t;                    // 0..131071
  if (gid < 65536) {                      // 65536 float4 = full out
    int g4 = (gid & 15)*4;
    const float* bb = (gid < 32768) ? bmu : bls;
    ((float4*)out)[gid] = make_float4(bb[g4], bb[g4+1], bb[g4+2], bb[g4+3]);
  }

  if (b < 128) {
    int c0 = t*4;
    float cs0=0.f, cs1=0.f, cs2=0.f, cs3=0.f;
    #pragma unroll 2
    for (int rr=0; rr<8; ++rr){
      int r = b*8 + rr;
      float4 v = *(const float4*)(my + (size_t)r*NN + c0);
      float s0=sigm(v.x), s1=sigm(v.y), s2=sigm(v.z), s3=sigm(v.w);
      *(float4*)(SpRaw + (size_t)r*HALF + c0) = make_float4(s0,s1,s2,s3);
      cs0+=s0; cs1+=s1; cs2+=s2; cs3+=s3;
    }
    atomicAdd(&colsum[c0+0], cs0);
    atomicAdd(&colsum[c0+1], cs1);
    atomicAdd(&colsum[c0+2], cs2);
    atomicAdd(&colsum[c0+3], cs3);
  } else if (b < 256) {
    int e0 = (b-128)*512 + t;
    #pragma unroll
    for (int i=0;i<2;i++){
      int e = e0 + i*256;
      int s = ei[e], d = ei[EE + e];
      int slot = atomicAdd(&cnt[d], 1);
      if (slot < CAP) bucket[d*CAP + slot] = (u16)s;
    }
  } else {
    int row0 = (b-256)*8;
    #pragma unroll
    for (int i=0;i<4;i++){
      int idx = i*256 + t;
      la[idx>>7][idx&127] = x[(size_t)row0*CC + idx];
    }
    __syncthreads();
    int f = t & 127, rh = t >> 7;
    const float4* a0 = (const float4*)la[rh*4+0];
    const float4* a1 = (const float4*)la[rh*4+1];
    const float4* a2 = (const float4*)la[rh*4+2];
    const float4* a3 = (const float4*)la[rh*4+3];
    float o0=0.f, o1=0.f, o2=0.f, o3=0.f;
    #pragma unroll 4
    for (int k4=0;k4<32;k4++){
      float4 v0=a0[k4], v1=a1[k4], v2=a2[k4], v3=a3[k4];
      float w0 = W1[(k4*4+0)*CC + f];
      float w1 = W1[(k4*4+1)*CC + f];
      float w2 = W1[(k4*4+2)*CC + f];
      float w3 = W1[(k4*4+3)*CC + f];
      o0=fmaf(v0.x,w0,o0); o0=fmaf(v0.y,w1,o0); o0=fmaf(v0.z,w2,o0); o0=fmaf(v0.w,w3,o0);
      o1=fmaf(v1.x,w0,o1); o1=fmaf(v1.y,w1,o1); o1=fmaf(v1.z,w2,o1); o1=fmaf(v1.w,w3,o1);
      o2=fmaf(v2.x,w0,o2); o2=fmaf(v2.y,w1,o2); o2=fmaf(v2.z,w2,o2); o2=fmaf(v2.w,w3,o2);
      o3=fmaf(v3.x,w0,o3); o3=fmaf(v3.y,w1,o3); o3=fmaf(v3.z,w2,o3); o3=fmaf(v3.w,w3,o3);
    }
    H0[(size_t)(row0 + rh*4 + 0)*CC + f] = o0;
    H0[(size_t)(row0 + rh*4 + 1)*CC + f] = o1;
    H0[(size_t)(row0 + rh*4 + 2)*CC + f] = o2;
    H0[(size_t)(row0 + rh*4 + 3)*CC + f] = o3;
  }
}

// ---------------- K2: layer1 partials (768 blocks, NO atomics)
//  dense [0,512): 8 r-chunks of 128, 16 d/block -> DP[chunk][d][f]
//  sparse [512,768): 8 dst/block, half-wave float4 -> SP[d][f]
__global__ __launch_bounds__(256) void k_layer1(
  const float* __restrict__ SpRaw, const float* __restrict__ H0,
  const int* __restrict__ cnt, const float* __restrict__ colsum,
  const u16* __restrict__ bucket,
  float* __restrict__ SP, float* __restrict__ DP)
{
  int b = blockIdx.x, t = threadIdx.x;
  if (b < 512) {
    __shared__ float srow[128];
    int chunk = b & 7, r0 = chunk*128;
    if (t < 128) srow[t] = dinv_lo(r0 + t, cnt, colsum);
    __syncthreads();
    int lane = t & 63, f0 = lane*2;
    int dbase = (b>>3)*16 + (t>>6)*4;
    float a00=0.f,a01=0.f,a10=0.f,a11=0.f,a20=0.f,a21=0.f,a30=0.f,a31=0.f;
    #pragma unroll 4
    for (int rr=0; rr<128; ++rr){
      int r = r0 + rr;
      float2 fv = *(const float2*)(H0 + (size_t)r*CC + f0);
      float sc = srow[rr];
      float fx = fv.x*sc, fy = fv.y*sc;
      float4 s4 = *(const float4*)(SpRaw + (size_t)r*HALF + dbase);
      a00=fmaf(s4.x,fx,a00); a01=fmaf(s4.x,fy,a01);
      a10=fmaf(s4.y,fx,a10); a11=fmaf(s4.y,fy,a11);
      a20=fmaf(s4.z,fx,a20); a21=fmaf(s4.z,fy,a21);
      a30=fmaf(s4.w,fx,a30); a31=fmaf(s4.w,fy,a31);
    }
    float d0=dinv_lo(dbase+0,cnt,colsum), d1=dinv_lo(dbase+1,cnt,colsum);
    float d2=dinv_lo(dbase+2,cnt,colsum), d3=dinv_lo(dbase+3,cnt,colsum);
    float* o = DP + ((size_t)chunk*HALF + dbase)*CC + f0;
    o[0*CC+0]=a00*d0; o[0*CC+1]=a01*d0;
    o[1*CC+0]=a10*d1; o[1*CC+1]=a11*d1;
    o[2*CC+0]=a20*d2; o[2*CC+1]=a21*d2;
    o[3*CC+0]=a30*d3; o[3*CC+1]=a31*d3;
  } else {
    __shared__ float sdinv[NN];
    #pragma unroll
    for (int i=0;i<8;i++){
      int j = i*256 + t;
      float cs = (j < HALF) ? colsum[j] : 0.0f;
      sdinv[j] = rsqrtf(1.0f + (float)cnt[j] + cs);
    }
    __syncthreads();
    int w = t>>6, hw = (t>>5)&1, l = t&31;
    int d = (b-512)*8 + w*2 + hw;
    int f0 = l*4;
    float dd = sdinv[d];
    float4 sv = *(const float4*)(H0 + (size_t)d*CC + f0);
    float ax=dd*sv.x, ay=dd*sv.y, az=dd*sv.z, aw=dd*sv.w;   // self-loop
    int m = cnt[d]; m = m > CAP ? CAP : m;
    const u16* bk = bucket + d*CAP;
    int j = 0;
    for (; j+1 < m; j += 2){
      unsigned pr = *(const unsigned*)(bk + j);
      int s0 = pr & 0xffff, s1 = pr >> 16;
      float w0 = sdinv[s0], w1 = sdinv[s1];
      float4 v0 = *(const float4*)(H0 + (size_t)s0*CC + f0);
      float4 v1 = *(const float4*)(H0 + (size_t)s1*CC + f0);
      ax=fmaf(w0,v0.x,ax); ay=fmaf(w0,v0.y,ay); az=fmaf(w0,v0.z,az); aw=fmaf(w0,v0.w,aw);
      ax=fmaf(w1,v1.x,ax); ay=fmaf(w1,v1.y,ay); az=fmaf(w1,v1.z,az); aw=fmaf(w1,v1.w,aw);
    }
    if (j < m){
      int s0 = bk[j];
      float w0 = sdinv[s0];
      float4 v0 = *(const float4*)(H0 + (size_t)s0*CC + f0);
      ax=fmaf(w0,v0.x,ax); ay=fmaf(w0,v0.y,ay); az=fmaf(w0,v0.z,az); aw=fmaf(w0,v0.w,aw);
    }
    *(float4*)(SP + (size_t)d*CC + f0) = make_float4(dd*ax, dd*ay, dd*az, dd*aw);
  }
}

// ---------------- K3: mid (512 blocks, 4 rows each)
//  Gm = (relu(SP + sum_8 DP + b1) @ [Wmu|Wls]) * dinv[row]
__global__ __launch_bounds__(256) void k_mid(
  const float* __restrict__ SP, const float* __restrict__ DP,
  const float* __restrict__ b1,
  const float* __restrict__ Wmu, const float* __restrict__ Wls,
  const int* __restrict__ cnt, const float* __restrict__ colsum,
  float* __restrict__ Gm)
{
  __shared__ float la[4][CC];
  int b = blockIdx.x, t = threadIdx.x;
  int row0 = b*4;
  #pragma unroll
  for (int i=0;i<2;i++){
    int idx = i*256 + t;                  // 0..511 covers 4 rows x 128
    int r = row0 + (idx>>7), c = idx & 127;
    float v = SP[(size_t)r*CC + c];
    if (r < HALF){
      #pragma unroll
      for (int k=0;k<8;k++) v += DP[((size_t)k*HALF + r)*CC + c];
    }
    v += b1[c];
    la[idx>>7][c] = v > 0.f ? v : 0.f;
  }
  __syncthreads();
  int f = t & 127, rh = t >> 7, g = f & 63;
  const float* W = (f < 64) ? Wmu : Wls;
  const float4* a0 = (const float4*)la[rh*2+0];
  const float4* a1 = (const float4*)la[rh*2+1];
  float o0=0.f, o1=0.f;
  #pragma unroll 4
  for (int k4=0;k4<32;k4++){
    float4 v0=a0[k4], v1=a1[k4];
    float w0 = W[(k4*4+0)*64 + g];
    float w1 = W[(k4*4+1)*64 + g];
    float w2 = W[(k4*4+2)*64 + g];
    float w3 = W[(k4*4+3)*64 + g];
    o0=fmaf(v0.x,w0,o0); o0=fmaf(v0.y,w1,o0); o0=fmaf(v0.z,w2,o0); o0=fmaf(v0.w,w3,o0);
    o1=fmaf(v1.x,w0,o1); o1=fmaf(v1.y,w1,o1); o1=fmaf(v1.z,w2,o1); o1=fmaf(v1.w,w3,o1);
  }
  int rA = row0 + rh*2;
  Gm[(size_t)(rA+0)*CC + f] = o0 * dinv_any(rA+0, cnt, colsum);
  Gm[(size_t)(rA+1)*CC + f] = o1 * dinv_any(rA+1, cnt, colsum);
}

// ---------------- K4: layer2 -> atomics into bias-seeded out (768 blocks)
//  dense [0,512): 8 r-chunks of 128; sparse [512,768): 8 dst/block half-wave float4
__global__ __launch_bounds__(256) void k_layer2(
  const float* __restrict__ SpRaw, const float* __restrict__ Gm,
  const int* __restrict__ cnt, const float* __restrict__ colsum,
  const u16* __restrict__ bucket, float* __restrict__ out)
{
  int b = blockIdx.x, t = threadIdx.x;
  if (b < 512) {
    int lane = t & 63, f0 = lane*2;
    size_t obase = (f0 < 64) ? 0 : (size_t)NN*64;
    int g0 = f0 & 63;
    int dbase = (b>>3)*16 + (t>>6)*4;
    int r0 = (b&7)*128;
    float a00=0.f,a01=0.f,a10=0.f,a11=0.f,a20=0.f,a21=0.f,a30=0.f,a31=0.f;
    #pragma unroll 4
    for (int rr=0; rr<128; ++rr){
      int r = r0 + rr;
      float2 gv = *(const float2*)(Gm + (size_t)r*CC + f0);   // pre-scaled by dinv[r]
      float4 s4 = *(const float4*)(SpRaw + (size_t)r*HALF + dbase);
      a00=fmaf(s4.x,gv.x,a00); a01=fmaf(s4.x,gv.y,a01);
      a10=fmaf(s4.y,gv.x,a10); a11=fmaf(s4.y,gv.y,a11);
      a20=fmaf(s4.z,gv.x,a20); a21=fmaf(s4.z,gv.y,a21);
      a30=fmaf(s4.w,gv.x,a30); a31=fmaf(s4.w,gv.y,a31);
    }
    float d0=dinv_lo(dbase+0,cnt,colsum), d1=dinv_lo(dbase+1,cnt,colsum);
    float d2=dinv_lo(dbase+2,cnt,colsum), d3=dinv_lo(dbase+3,cnt,colsum);
    float* o = out + obase + (size_t)dbase*64 + g0;
    atomicAdd(o + 0*64 + 0, a00*d0); atomicAdd(o + 0*64 + 1, a01*d0);
    atomicAdd(o + 1*64 + 0, a10*d1); atomicAdd(o + 1*64 + 1, a11*d1);
    atomicAdd(o + 2*64 + 0, a20*d2); atomicAdd(o + 2*64 + 1, a21*d2);
    atomicAdd(o + 3*64 + 0, a30*d3); atomicAdd(o + 3*64 + 1, a31*d3);
  } else {
    int w = t>>6, hw = (t>>5)&1, l = t&31;
    int d = (b-512)*8 + w*2 + hw;
    int f0 = l*4;
    size_t obase = (f0 < 64) ? 0 : (size_t)NN*64;
    int g0 = f0 & 63;
    float4 a = *(const float4*)(Gm + (size_t)d*CC + f0);      // self (pre-scaled)
    float ax=a.x, ay=a.y, az=a.z, aw=a.w;
    int m = cnt[d]; m = m > CAP ? CAP : m;
    const u16* bk = bucket + d*CAP;
    int j = 0;
    for (; j+1 < m; j += 2){
      unsigned pr = *(const unsigned*)(bk + j);
      int s0 = pr & 0xffff, s1 = pr >> 16;
      float4 v0 = *(const float4*)(Gm + (size_t)s0*CC + f0);
      float4 v1 = *(const float4*)(Gm + (size_t)s1*CC + f0);
      ax += v0.x + v1.x; ay += v0.y + v1.y;
      az += v0.z + v1.z; aw += v0.w + v1.w;
    }
    if (j < m){
      int s0 = bk[j];
      float4 v0 = *(const float4*)(Gm + (size_t)s0*CC + f0);
      ax += v0.x; ay += v0.y; az += v0.z; aw += v0.w;
    }
    float dd = dinv_any(d, cnt, colsum);
    float* o = out + obase + (size_t)d*64 + g0;
    atomicAdd(o + 0, dd*ax); atomicAdd(o + 1, dd*ay);
    atomicAdd(o + 2, dd*az); atomicAdd(o + 3, dd*aw);
  }
}

extern "C" void kernel_launch(void* const* d_in, const int* in_sizes, int n_in,
                              void* d_out, int out_size, void* d_ws, size_t ws_size,
                              hipStream_t stream)
{
  (void)in_sizes; (void)n_in; (void)out_size; (void)ws_size;
  const float* x   = (const float*)d_in[0];
  const float* my  = (const float*)d_in[1];
  const float* W1  = (const float*)d_in[2];
  const float* b1  = (const float*)d_in[3];
  const float* Wmu = (const float*)d_in[4];
  const float* bmu = (const float*)d_in[5];
  const float* Wls = (const float*)d_in[6];
  const float* bls = (const float*)d_in[7];
  const int*   ei  = (const int*)d_in[8];
  float* out = (float*)d_out;
  char* ws = (char*)d_ws;

  // ws layout — memset covers [0, 12288): cnt, colsum
  int*   cnt    = (int*)  (ws + 0);        //    8192 B (memset 0)
  float* colsum = (float*)(ws + 8192);     //    4096 B (memset 0)
  u16*   bucket = (u16*)  (ws + 12288);    //  524288 B
  float* SpRaw  = (float*)(ws + 536576);   // 4194304 B
  float* H0     = (float*)(ws + 4730880);  // 1048576 B
  float* Gm     = (float*)(ws + 5779456);  // 1048576 B
  float* SP     = (float*)(ws + 6828032);  // 1048576 B
  float* DP     = (float*)(ws + 7876608);  // 4194304 B  (8*1024*128*4)

  hipMemsetAsync(ws, 0, 12288, stream);
  k_prep  <<<512, 256, 0, stream>>>(my, ei, x, W1, bmu, bls,
                                    SpRaw, colsum, cnt, bucket, H0, out);
  k_layer1<<<768, 256, 0, stream>>>(SpRaw, H0, cnt, colsum, bucket, SP, DP);
  k_mid   <<<512, 256, 0, stream>>>(SP, DP, b1, Wmu, Wls, cnt, colsum, Gm);
  k_layer2<<<768, 256, 0, stream>>>(SpRaw, Gm, cnt, colsum, bucket, out);
}